// Round 1
// 435.194 us; speedup vs baseline: 1.0147x; 1.0147x over previous
//
#include <hip/hip_runtime.h>
#include <hip/hip_bf16.h>
#include <math.h>

#define Bb 64
#define Ll 2048
#define Ff 100
#define Dd 1024
#define NC 50000
#define NBLK3 782   // ceil(50000/64)

typedef __attribute__((ext_vector_type(8))) short short8;
typedef __attribute__((ext_vector_type(4))) float floatx4;

union frag_u { short8 s8; unsigned u[4]; uint4 u4; };

__device__ __forceinline__ unsigned cvt2bf(float x, float y) {
    __hip_bfloat162 h = __float22bfloat162_rn(make_float2(x, y));
    unsigned r; __builtin_memcpy(&r, &h, 4); return r;
}

// ---------------------------------------------------------------------------
// K0: pack conv_w -> bf16 MFMA B-fragment order:
// wp[(((ds*4+kc)*4+quad)*16+col)*8 + j] = bf16(conv_w[ds*16+col][kc*32+quad*8+j])
// (zero-padded past k=100). One wave B-frag load = contiguous 1 KB segment.
// ---------------------------------------------------------------------------
__global__ __launch_bounds__(256)
void k0_pack_w(const float* __restrict__ conv_w, unsigned short* __restrict__ wp)
{
    const int t = blockIdx.x * 256 + threadIdx.x;   // 16384
    const int col = t & 15, quad = (t >> 4) & 3, kc = (t >> 6) & 3, ds = t >> 8;
    const int d = ds * 16 + col, k0 = kc * 32 + quad * 8;
    unsigned short v[8];
    #pragma unroll
    for (int j = 0; j < 8; ++j) {
        int k = k0 + j;
        float f = (k < Ff) ? conv_w[(size_t)d * Ff + k] : 0.f;
        unsigned u = cvt2bf(f, 0.f);
        v[j] = (unsigned short)(u & 0xFFFFu);
    }
    *(uint4*)(wp + (size_t)t * 8) = *(uint4*)v;
}

// ---------------------------------------------------------------------------
// K1: max_l (x[b,l,:] . conv_w[d,:]) via bf16 MFMA.
// grid(64 b, 16 lw) = 1024 blocks. Block = 128 l x ALL 1024 d; x tile staged
// to LDS ONCE (34.8 KB, single __syncthreads). Wave owns 256 d.
// Per-block partial max -> pmax[b][lw][d] (plain stores, no atomics).
// ---------------------------------------------------------------------------
__global__ __launch_bounds__(256, 2)
void k1_conv_mfma(const float* __restrict__ x,
                  const unsigned short* __restrict__ wp,
                  float* __restrict__ pmax)
{
    const int b    = blockIdx.x;
    const int lw   = blockIdx.y;
    const int tid  = threadIdx.x;
    const int wave = tid >> 6, lane = tid & 63;
    const int quad = lane >> 4, col = lane & 15;

    __shared__ __align__(16) unsigned short xs[128 * 136];

    // zero k-pad (cols 100..135)
    for (int i = tid; i < 128 * 18; i += 256) {
        int row = i / 18, c = i % 18;
        *(unsigned*)&xs[row * 136 + 100 + c * 2] = 0u;
    }
    // stage x[b, lw*128..+127][0..99] -> bf16
    {
        const float* xw = x + ((size_t)b * Ll + (size_t)lw * 128) * Ff;
        #pragma unroll
        for (int j = 0; j < 13; ++j) {
            int idx = tid + j * 256;
            if (idx < 3200) {
                float4 v = *(const float4*)(xw + idx * 4);
                int row = idx / 25, c4 = idx % 25;
                *(uint2*)&xs[row * 136 + c4 * 4] =
                    make_uint2(cvt2bf(v.x, v.y), cvt2bf(v.z, v.w));
            }
        }
    }
    __syncthreads();

    const floatx4 zz = {0.f, 0.f, 0.f, 0.f};
    float mx[16];
    #pragma unroll
    for (int i = 0; i < 16; ++i) mx[i] = -INFINITY;

    #pragma unroll 1
    for (int g = 0; g < 4; ++g) {
        // B-fragments for 4 d-subtiles x 4 kc (coalesced 1KB segments)
        frag_u B[4][4];
        #pragma unroll
        for (int i = 0; i < 4; ++i) {
            const int ds = wave * 16 + g * 4 + i;
            #pragma unroll
            for (int kc = 0; kc < 4; ++kc)
                B[i][kc].u4 = *(const uint4*)(wp +
                    ((size_t)(ds * 4 + kc) * 64 + lane) * 8);
        }
        #pragma unroll 1
        for (int m = 0; m < 8; ++m) {
            frag_u A[4];
            #pragma unroll
            for (int kc = 0; kc < 4; ++kc)
                A[kc].s8 = *(const short8*)&xs[(m * 16 + col) * 136 + kc * 32 + quad * 8];
            floatx4 acc[4];
            #pragma unroll
            for (int i = 0; i < 4; ++i)
                acc[i] = __builtin_amdgcn_mfma_f32_16x16x32_bf16(A[0].s8, B[i][0].s8, zz, 0, 0, 0);
            #pragma unroll
            for (int kc = 1; kc < 4; ++kc)
                #pragma unroll
                for (int i = 0; i < 4; ++i)
                    acc[i] = __builtin_amdgcn_mfma_f32_16x16x32_bf16(A[kc].s8, B[i][kc].s8, acc[i], 0, 0, 0);
            #pragma unroll
            for (int i = 0; i < 4; ++i)
                #pragma unroll
                for (int r = 0; r < 4; ++r)
                    mx[g * 4 + i] = fmaxf(mx[g * 4 + i], acc[i][r]);
        }
    }

    #pragma unroll
    for (int gi = 0; gi < 16; ++gi) {
        float mm = mx[gi];
        mm = fmaxf(mm, __shfl_xor(mm, 16, 64));
        mm = fmaxf(mm, __shfl_xor(mm, 32, 64));
        if (quad == 0) {
            const int d = (wave * 16 + gi) * 16 + col;
            pmax[((size_t)b * 16 + lw) * Dd + d] = mm;
        }
    }
}

// ---------------------------------------------------------------------------
// K1b: pooled[b][d] = elu(max_lw pmax[b][lw][d] + conv_b[d])
// 65536 threads; consecutive threads = consecutive d -> coalesced per lw pass.
// ---------------------------------------------------------------------------
__global__ __launch_bounds__(256)
void k1b_pool(const float* __restrict__ pmax,
              const float* __restrict__ conv_b,
              float* __restrict__ pooled)
{
    const int i = blockIdx.x * 256 + threadIdx.x;   // 65536
    const int b = i >> 10, d = i & (Dd - 1);
    const float* p = pmax + (size_t)b * 16 * Dd + d;
    float m = -INFINITY;
    #pragma unroll
    for (int lw = 0; lw < 16; ++lw) m = fmaxf(m, p[lw * Dd]);
    m += conv_b[d];
    pooled[i] = (m > 0.f) ? m : expm1f(m);
}

// ---------------------------------------------------------------------------
// K2: out2[b][d] = relu(pooled[b,:] . lin_w[d,:] + lin_b[d])
// d-major: grid(64 dt, 4 bgrp). Block owns 16 d; lin_w rows held in REGISTERS
// (16 float4/thread) and reused across 16 b -> lin_w traffic 268 MB -> 16 MB.
// ---------------------------------------------------------------------------
__global__ __launch_bounds__(256)
void k2_linear(const float* __restrict__ pooled,
               const float* __restrict__ lin_w,
               const float* __restrict__ lin_b,
               float* __restrict__ out2)
{
    const int dt = blockIdx.x;            // 0..63
    const int b0 = blockIdx.y * 16;       // 0..3 -> 16 b each
    const int tid = threadIdx.x;
    const int dl = tid >> 4, kq = tid & 15;
    const int d = dt * 16 + dl;
    const float* wr = lin_w + (size_t)d * Dd;
    float4 w[16];
    #pragma unroll
    for (int i = 0; i < 16; ++i) w[i] = *(const float4*)(wr + i * 64 + kq * 4);
    const float bias = lin_b[d];

    #pragma unroll 2
    for (int bb = 0; bb < 16; ++bb) {
        const float* pr = pooled + (size_t)(b0 + bb) * Dd;
        float ax = 0.f, ay = 0.f, az = 0.f, aw = 0.f;
        #pragma unroll
        for (int i = 0; i < 16; ++i) {
            float4 pv = *(const float4*)(pr + i * 64 + kq * 4);
            ax = fmaf(w[i].x, pv.x, ax); ay = fmaf(w[i].y, pv.y, ay);
            az = fmaf(w[i].z, pv.z, az); aw = fmaf(w[i].w, pv.w, aw);
        }
        float acc = (ax + ay) + (az + aw);
        acc += __shfl_xor(acc, 1, 64);
        acc += __shfl_xor(acc, 2, 64);
        acc += __shfl_xor(acc, 4, 64);
        acc += __shfl_xor(acc, 8, 64);
        if (kq == 0)
            out2[(size_t)(b0 + bb) * Dd + d] = fmaxf(acc + bias, 0.f);
    }
}

// ---------------------------------------------------------------------------
// K2b: row-norm computed in-block (no normsq workspace / atomics), then
// xnbf[b][d] = bf16( out2[b][d] / max(||out2[b]||, eps) )
// ---------------------------------------------------------------------------
__global__ __launch_bounds__(256)
void k2b_norm_cvt(const float* __restrict__ out2,
                  unsigned short* __restrict__ xnbf)
{
    const int b = blockIdx.x, tid = threadIdx.x;
    float4 v = *(const float4*)(out2 + (size_t)b * Dd + tid * 4);
    float ss = v.x * v.x + v.y * v.y + v.z * v.z + v.w * v.w;
    ss += __shfl_xor(ss, 1, 64);  ss += __shfl_xor(ss, 2, 64);
    ss += __shfl_xor(ss, 4, 64);  ss += __shfl_xor(ss, 8, 64);
    ss += __shfl_xor(ss, 16, 64); ss += __shfl_xor(ss, 32, 64);
    __shared__ float ws4[4];
    __shared__ float rsh;
    if ((tid & 63) == 0) ws4[tid >> 6] = ss;
    __syncthreads();
    if (tid == 0)
        rsh = 1.f / fmaxf(sqrtf(ws4[0] + ws4[1] + ws4[2] + ws4[3]), 1e-12f);
    __syncthreads();
    const float r = rsh;
    unsigned* p = (unsigned*)(xnbf + (size_t)b * Dd + tid * 4);
    p[0] = cvt2bf(v.x * r, v.y * r);
    p[1] = cvt2bf(v.z * r, v.w * r);
}

// ---------------------------------------------------------------------------
// K3: e[b][n] = exp(xn[b,:] . embed[n,:]) via bf16 MFMA — LDS-FREE.
// B-frags of embed load straight from global (16 rows x 128B segments per
// wave = fully coalesced), cvt to bf16 in registers; A-frags from xnbf are
// L2-hot. No __syncthreads in the K-loop; 1-deep register double-buffer on
// the embed (HBM-critical) stream. grid(782): 64 n x 64 b per block, 4 waves.
// ---------------------------------------------------------------------------
__global__ __launch_bounds__(256, 2)
void k3_logits_mfma(const float* __restrict__ embed,
                    const unsigned short* __restrict__ xnbf,
                    float* __restrict__ out,
                    float* __restrict__ partials)
{
    const int tid  = threadIdx.x;
    const int wave = tid >> 6, lane = tid & 63;
    const int quad = lane >> 4, col = lane & 15;
    const int n0   = blockIdx.x * 64;
    const int n    = n0 + wave * 16 + col;
    const bool vn  = (n < NC);
    const int gn   = vn ? n : (NC - 1);

    const float* ep = embed + (size_t)gn * Dd + quad * 8;
    const unsigned short* ap = xnbf + (size_t)col * Dd + quad * 8;

    const floatx4 zz = {0.f, 0.f, 0.f, 0.f};
    floatx4 acc[4] = {zz, zz, zz, zz};

    // embed register double-buffer: eb[buf][j] = 8 floats per ks-half
    float4 eb[2][4];
    #pragma unroll
    for (int j = 0; j < 2; ++j) {
        eb[0][2 * j]     = *(const float4*)(ep + j * 32);
        eb[0][2 * j + 1] = *(const float4*)(ep + j * 32 + 4);
    }

    #pragma unroll
    for (int c = 0; c < 16; ++c) {
        const int cur = c & 1;
        if (c < 15) {
            #pragma unroll
            for (int j = 0; j < 2; ++j) {
                eb[cur ^ 1][2 * j]     = *(const float4*)(ep + (c + 1) * 64 + j * 32);
                eb[cur ^ 1][2 * j + 1] = *(const float4*)(ep + (c + 1) * 64 + j * 32 + 4);
            }
        }
        frag_u bf[2];
        #pragma unroll
        for (int ks = 0; ks < 2; ++ks) {
            bf[ks].u[0] = cvt2bf(eb[cur][2 * ks].x,     eb[cur][2 * ks].y);
            bf[ks].u[1] = cvt2bf(eb[cur][2 * ks].z,     eb[cur][2 * ks].w);
            bf[ks].u[2] = cvt2bf(eb[cur][2 * ks + 1].x, eb[cur][2 * ks + 1].y);
            bf[ks].u[3] = cvt2bf(eb[cur][2 * ks + 1].z, eb[cur][2 * ks + 1].w);
        }
        #pragma unroll
        for (int ks = 0; ks < 2; ++ks)
            #pragma unroll
            for (int s = 0; s < 4; ++s) {
                frag_u af;
                af.u4 = *(const uint4*)(ap + (size_t)s * 16 * Dd + c * 64 + ks * 32);
                acc[s] = __builtin_amdgcn_mfma_f32_16x16x32_bf16(
                    af.s8, bf[ks].s8, acc[s], 0, 0, 0);
            }
    }

    __shared__ float bpart[4][64];
    float e[4][4];
    #pragma unroll
    for (int s = 0; s < 4; ++s)
        #pragma unroll
        for (int r = 0; r < 4; ++r) {
            float v = vn ? __expf(acc[s][r]) : 0.f;
            e[s][r] = v;
            if (vn) out[(size_t)(s * 16 + quad * 4 + r) * NC + n] = v;
        }
    #pragma unroll
    for (int s = 0; s < 4; ++s)
        #pragma unroll
        for (int r = 0; r < 4; ++r) {
            float v = e[s][r];
            v += __shfl_xor(v, 1, 64); v += __shfl_xor(v, 2, 64);
            v += __shfl_xor(v, 4, 64); v += __shfl_xor(v, 8, 64);
            if (col == 0) bpart[wave][s * 16 + quad * 4 + r] = v;
        }
    __syncthreads();
    if (tid < 64)
        partials[(size_t)blockIdx.x * 64 + tid] =
            bpart[0][tid] + bpart[1][tid] + bpart[2][tid] + bpart[3][tid];
}

// ---------------------------------------------------------------------------
// K3b: rsum[b] = 1 / sum_k partials[k][b]   grid(64): one b per block
// ---------------------------------------------------------------------------
__global__ __launch_bounds__(256)
void k3b_reduce(const float* __restrict__ partials,
                float* __restrict__ rsum)
{
    const int b = blockIdx.x, tid = threadIdx.x;
    float a = 0.f;
    for (int k = tid; k < NBLK3; k += 256)
        a += partials[(size_t)k * 64 + b];
    a += __shfl_xor(a, 1, 64);  a += __shfl_xor(a, 2, 64);
    a += __shfl_xor(a, 4, 64);  a += __shfl_xor(a, 8, 64);
    a += __shfl_xor(a, 16, 64); a += __shfl_xor(a, 32, 64);
    __shared__ float wsum[4];
    if ((tid & 63) == 0) wsum[tid >> 6] = a;
    __syncthreads();
    if (tid == 0)
        rsum[b] = 1.f / (wsum[0] + wsum[1] + wsum[2] + wsum[3]);
}

// ---------------------------------------------------------------------------
// K4: out[b][n] *= rsum[b]
// ---------------------------------------------------------------------------
__global__ __launch_bounds__(256)
void k4_scale(float* __restrict__ out, const float* __restrict__ rsum)
{
    const int b  = blockIdx.y;
    const int n4 = (blockIdx.x * 256 + threadIdx.x) * 4;
    if (n4 >= NC) return;
    const float r = rsum[b];
    float4* p = (float4*)(out + (size_t)b * NC + n4);
    float4 v = *p;
    v.x *= r; v.y *= r; v.z *= r; v.w *= r;
    *p = v;
}

extern "C" void kernel_launch(void* const* d_in, const int* in_sizes, int n_in,
                              void* d_out, int out_size, void* d_ws, size_t ws_size,
                              hipStream_t stream)
{
    const float* x      = (const float*)d_in[0];
    const float* embed  = (const float*)d_in[1];
    const float* conv_w = (const float*)d_in[2];
    const float* conv_b = (const float*)d_in[3];
    const float* lin_w  = (const float*)d_in[4];
    const float* lin_b  = (const float*)d_in[5];
    float* out = (float*)d_out;
    float* ws  = (float*)d_ws;

    // workspace layout (floats) — every region fully written before read;
    // no memset required.
    unsigned short* wpack = (unsigned short*)ws;            // 131072 shorts
    float* pmax   = ws + 65536;                             // 64*16*1024 = 1,048,576
    float* pooled = ws + 1114112;                           // 65536
    float* out2   = ws + 1179648;                           // 65536
    unsigned short* xnbf = (unsigned short*)(ws + 1245184); // 65536 bf16
    float* partials = ws + 1277952;                         // 50048
    float* rsum   = ws + 1328000;                           // 64

    k0_pack_w   <<<dim3(64),      256, 0, stream>>>(conv_w, wpack);
    k1_conv_mfma<<<dim3(64, 16),  256, 0, stream>>>(x, wpack, pmax);
    k1b_pool    <<<dim3(256),     256, 0, stream>>>(pmax, conv_b, pooled);
    k2_linear   <<<dim3(64, 4),   256, 0, stream>>>(pooled, lin_w, lin_b, out2);
    k2b_norm_cvt<<<dim3(64),      256, 0, stream>>>(out2, xnbf);
    k3_logits_mfma<<<dim3(NBLK3), 256, 0, stream>>>(embed, xnbf, out, partials);
    k3b_reduce  <<<dim3(64),      256, 0, stream>>>(partials, rsum);
    k4_scale    <<<dim3(49, 64),  256, 0, stream>>>(out, rsum);
}

// Round 2
// 421.129 us; speedup vs baseline: 1.0486x; 1.0334x over previous
//
#include <hip/hip_runtime.h>
#include <hip/hip_bf16.h>
#include <math.h>

#define Bb 64
#define Ll 2048
#define Ff 100
#define Dd 1024
#define NC 50000
#define NBLK3 782   // ceil(50000/64)

typedef __attribute__((ext_vector_type(8))) short short8;
typedef __attribute__((ext_vector_type(4))) float floatx4;

union frag_u { short8 s8; unsigned u[4]; uint4 u4; };

__device__ __forceinline__ unsigned cvt2bf(float x, float y) {
    __hip_bfloat162 h = __float22bfloat162_rn(make_float2(x, y));
    unsigned r; __builtin_memcpy(&r, &h, 4); return r;
}

// ---------------------------------------------------------------------------
// K0: pack conv_w -> bf16 MFMA B-fragment order:
// wp[(((ds*4+kc)*4+quad)*16+col)*8 + j] = bf16(conv_w[ds*16+col][kc*32+quad*8+j])
// (zero-padded past k=100). One wave B-frag load = contiguous 1 KB segment.
// ---------------------------------------------------------------------------
__global__ __launch_bounds__(256)
void k0_pack_w(const float* __restrict__ conv_w, unsigned short* __restrict__ wp)
{
    const int t = blockIdx.x * 256 + threadIdx.x;   // 16384
    const int col = t & 15, quad = (t >> 4) & 3, kc = (t >> 6) & 3, ds = t >> 8;
    const int d = ds * 16 + col, k0 = kc * 32 + quad * 8;
    unsigned short v[8];
    #pragma unroll
    for (int j = 0; j < 8; ++j) {
        int k = k0 + j;
        float f = (k < Ff) ? conv_w[(size_t)d * Ff + k] : 0.f;
        unsigned u = cvt2bf(f, 0.f);
        v[j] = (unsigned short)(u & 0xFFFFu);
    }
    *(uint4*)(wp + (size_t)t * 8) = *(uint4*)v;
}

// ---------------------------------------------------------------------------
// K1: max_l (x[b,l,:] . conv_w[d,:]) via bf16 MFMA.
// grid(64 b, 16 lw) = 1024 blocks. Block = 128 l x ALL 1024 d.
// x staged to LDS in MFMA A-FRAGMENT ORDER: slot (m,kc) of 520 shorts
// (1024B data + 16B pad); lane reads its 16B at slot + lane*16 -> contiguous
// wave-linear ds_read_b128, ZERO bank conflicts. Low register pressure:
// B[4][4] (64 VGPR) + acc[4] + single A frag + per-g mx[4] with immediate
// writeout => ~107 live VGPR, capped 128 via launch_bounds(256,4).
// ---------------------------------------------------------------------------
__global__ __launch_bounds__(256, 4)
void k1_conv_mfma(const float* __restrict__ x,
                  const unsigned short* __restrict__ wp,
                  float* __restrict__ pmax)
{
    const int b    = blockIdx.x;
    const int lw   = blockIdx.y;
    const int tid  = threadIdx.x;
    const int wave = tid >> 6, lane = tid & 63;
    const int quad = lane >> 4, col = lane & 15;

    // 32 slots (m=0..7, kc=0..3) x 520 shorts (16 lanes*... = 1024B + 16B pad)
    __shared__ __align__(16) unsigned short xs[32 * 520];

    // stage x[b, lw*128..+127][0..99] -> bf16, fragment order.
    // slot(m,kc) position (q*16+c)*8 + half*4 holds
    // x[row=m*16+c][k=kc*32+q*8+half*4 .. +3]
    {
        const float* xw = x + ((size_t)b * Ll + (size_t)lw * 128) * Ff;
        #pragma unroll
        for (int j = 0; j < 13; ++j) {
            int idx = tid + j * 256;
            if (idx < 3200) {
                float4 v = *(const float4*)(xw + idx * 4);
                int row = idx / 25, c4 = idx - row * 25;   // 4 floats each
                int m = row >> 4, cr = row & 15;
                int kc = c4 >> 3, rem = c4 & 7;
                int q = rem >> 1, half = rem & 1;
                int soff = (m * 4 + kc) * 520 + (q * 16 + cr) * 8 + half * 4;
                *(uint2*)&xs[soff] = make_uint2(cvt2bf(v.x, v.y), cvt2bf(v.z, v.w));
            }
        }
        // zero logical k = 100..127 (kc=3: chunks (q,half) = (0,1),(1,0)..(3,1))
        for (int i = tid; i < 128 * 7; i += 256) {
            int row = i / 7, c = i - (i / 7) * 7;
            int m = row >> 4, cr = row & 15;
            int q = (c + 1) >> 1, half = (c + 1) & 1;
            int soff = (m * 4 + 3) * 520 + (q * 16 + cr) * 8 + half * 4;
            *(uint2*)&xs[soff] = make_uint2(0u, 0u);
        }
    }
    __syncthreads();

    const floatx4 zz = {0.f, 0.f, 0.f, 0.f};
    const size_t prow = ((size_t)b * 16 + lw) * Dd;

    #pragma unroll 1
    for (int g = 0; g < 4; ++g) {
        // B-fragments: 4 d-subtiles x 4 kc (coalesced 1KB segments, L2-hot)
        frag_u B[4][4];
        #pragma unroll
        for (int i = 0; i < 4; ++i) {
            const int ds = wave * 16 + g * 4 + i;
            #pragma unroll
            for (int kc = 0; kc < 4; ++kc)
                B[i][kc].u4 = *(const uint4*)(wp +
                    ((size_t)(ds * 4 + kc) * 64 + lane) * 8);
        }

        float mx[4] = {-INFINITY, -INFINITY, -INFINITY, -INFINITY};

        #pragma unroll 1
        for (int m = 0; m < 8; ++m) {
            floatx4 acc[4];
            frag_u A;
            A.u4 = *(const uint4*)&xs[(m * 4 + 0) * 520 + lane * 8];
            #pragma unroll
            for (int i = 0; i < 4; ++i)
                acc[i] = __builtin_amdgcn_mfma_f32_16x16x32_bf16(A.s8, B[i][0].s8, zz, 0, 0, 0);
            #pragma unroll
            for (int kc = 1; kc < 4; ++kc) {
                frag_u A2;
                A2.u4 = *(const uint4*)&xs[(m * 4 + kc) * 520 + lane * 8];
                #pragma unroll
                for (int i = 0; i < 4; ++i)
                    acc[i] = __builtin_amdgcn_mfma_f32_16x16x32_bf16(A2.s8, B[i][kc].s8, acc[i], 0, 0, 0);
            }
            #pragma unroll
            for (int i = 0; i < 4; ++i) {
                // nested fmaxf pairs -> v_max3 fusion
                float t = fmaxf(fmaxf(acc[i][0], acc[i][1]), acc[i][2]);
                mx[i] = fmaxf(fmaxf(t, acc[i][3]), mx[i]);
            }
        }

        #pragma unroll
        for (int i = 0; i < 4; ++i) {
            float mm = mx[i];
            mm = fmaxf(mm, __shfl_xor(mm, 16, 64));
            mm = fmaxf(mm, __shfl_xor(mm, 32, 64));
            if (quad == 0) {
                const int d = (wave * 16 + g * 4 + i) * 16 + col;
                pmax[prow + d] = mm;
            }
        }
    }
}

// ---------------------------------------------------------------------------
// K1b: pooled[b][d] = elu(max_lw pmax[b][lw][d] + conv_b[d])
// 65536 threads; consecutive threads = consecutive d -> coalesced per lw pass.
// ---------------------------------------------------------------------------
__global__ __launch_bounds__(256)
void k1b_pool(const float* __restrict__ pmax,
              const float* __restrict__ conv_b,
              float* __restrict__ pooled)
{
    const int i = blockIdx.x * 256 + threadIdx.x;   // 65536
    const int b = i >> 10, d = i & (Dd - 1);
    const float* p = pmax + (size_t)b * 16 * Dd + d;
    float m = -INFINITY;
    #pragma unroll
    for (int lw = 0; lw < 16; ++lw) m = fmaxf(m, p[lw * Dd]);
    m += conv_b[d];
    pooled[i] = (m > 0.f) ? m : expm1f(m);
}

// ---------------------------------------------------------------------------
// K2: out2[b][d] = relu(pooled[b,:] . lin_w[d,:] + lin_b[d])
// d-major: grid(64 dt, 4 bgrp). Block owns 16 d; lin_w rows held in REGISTERS
// (16 float4/thread) and reused across 16 b -> lin_w traffic 268 MB -> 16 MB.
// ---------------------------------------------------------------------------
__global__ __launch_bounds__(256)
void k2_linear(const float* __restrict__ pooled,
               const float* __restrict__ lin_w,
               const float* __restrict__ lin_b,
               float* __restrict__ out2)
{
    const int dt = blockIdx.x;            // 0..63
    const int b0 = blockIdx.y * 16;       // 0..3 -> 16 b each
    const int tid = threadIdx.x;
    const int dl = tid >> 4, kq = tid & 15;
    const int d = dt * 16 + dl;
    const float* wr = lin_w + (size_t)d * Dd;
    float4 w[16];
    #pragma unroll
    for (int i = 0; i < 16; ++i) w[i] = *(const float4*)(wr + i * 64 + kq * 4);
    const float bias = lin_b[d];

    #pragma unroll 2
    for (int bb = 0; bb < 16; ++bb) {
        const float* pr = pooled + (size_t)(b0 + bb) * Dd;
        float ax = 0.f, ay = 0.f, az = 0.f, aw = 0.f;
        #pragma unroll
        for (int i = 0; i < 16; ++i) {
            float4 pv = *(const float4*)(pr + i * 64 + kq * 4);
            ax = fmaf(w[i].x, pv.x, ax); ay = fmaf(w[i].y, pv.y, ay);
            az = fmaf(w[i].z, pv.z, az); aw = fmaf(w[i].w, pv.w, aw);
        }
        float acc = (ax + ay) + (az + aw);
        acc += __shfl_xor(acc, 1, 64);
        acc += __shfl_xor(acc, 2, 64);
        acc += __shfl_xor(acc, 4, 64);
        acc += __shfl_xor(acc, 8, 64);
        if (kq == 0)
            out2[(size_t)(b0 + bb) * Dd + d] = fmaxf(acc + bias, 0.f);
    }
}

// ---------------------------------------------------------------------------
// K2b: row-norm computed in-block (no normsq workspace / atomics), then
// xnbf[b][d] = bf16( out2[b][d] / max(||out2[b]||, eps) )
// ---------------------------------------------------------------------------
__global__ __launch_bounds__(256)
void k2b_norm_cvt(const float* __restrict__ out2,
                  unsigned short* __restrict__ xnbf)
{
    const int b = blockIdx.x, tid = threadIdx.x;
    float4 v = *(const float4*)(out2 + (size_t)b * Dd + tid * 4);
    float ss = v.x * v.x + v.y * v.y + v.z * v.z + v.w * v.w;
    ss += __shfl_xor(ss, 1, 64);  ss += __shfl_xor(ss, 2, 64);
    ss += __shfl_xor(ss, 4, 64);  ss += __shfl_xor(ss, 8, 64);
    ss += __shfl_xor(ss, 16, 64); ss += __shfl_xor(ss, 32, 64);
    __shared__ float ws4[4];
    __shared__ float rsh;
    if ((tid & 63) == 0) ws4[tid >> 6] = ss;
    __syncthreads();
    if (tid == 0)
        rsh = 1.f / fmaxf(sqrtf(ws4[0] + ws4[1] + ws4[2] + ws4[3]), 1e-12f);
    __syncthreads();
    const float r = rsh;
    unsigned* p = (unsigned*)(xnbf + (size_t)b * Dd + tid * 4);
    p[0] = cvt2bf(v.x * r, v.y * r);
    p[1] = cvt2bf(v.z * r, v.w * r);
}

// ---------------------------------------------------------------------------
// K3: e[b][n] = exp(xn[b,:] . embed[n,:]) via bf16 MFMA — LDS-FREE.
// B-frags of embed load straight from global (16 rows x 128B segments per
// wave = fully coalesced), cvt to bf16 in registers; A-frags from xnbf are
// L2-hot. No __syncthreads in the K-loop; 1-deep register double-buffer on
// the embed (HBM-critical) stream. grid(782): 64 n x 64 b per block, 4 waves.
// ---------------------------------------------------------------------------
__global__ __launch_bounds__(256, 2)
void k3_logits_mfma(const float* __restrict__ embed,
                    const unsigned short* __restrict__ xnbf,
                    float* __restrict__ out,
                    float* __restrict__ partials)
{
    const int tid  = threadIdx.x;
    const int wave = tid >> 6, lane = tid & 63;
    const int quad = lane >> 4, col = lane & 15;
    const int n0   = blockIdx.x * 64;
    const int n    = n0 + wave * 16 + col;
    const bool vn  = (n < NC);
    const int gn   = vn ? n : (NC - 1);

    const float* ep = embed + (size_t)gn * Dd + quad * 8;
    const unsigned short* ap = xnbf + (size_t)col * Dd + quad * 8;

    const floatx4 zz = {0.f, 0.f, 0.f, 0.f};
    floatx4 acc[4] = {zz, zz, zz, zz};

    // embed register double-buffer: eb[buf][j] = 8 floats per ks-half
    float4 eb[2][4];
    #pragma unroll
    for (int j = 0; j < 2; ++j) {
        eb[0][2 * j]     = *(const float4*)(ep + j * 32);
        eb[0][2 * j + 1] = *(const float4*)(ep + j * 32 + 4);
    }

    #pragma unroll
    for (int c = 0; c < 16; ++c) {
        const int cur = c & 1;
        if (c < 15) {
            #pragma unroll
            for (int j = 0; j < 2; ++j) {
                eb[cur ^ 1][2 * j]     = *(const float4*)(ep + (c + 1) * 64 + j * 32);
                eb[cur ^ 1][2 * j + 1] = *(const float4*)(ep + (c + 1) * 64 + j * 32 + 4);
            }
        }
        frag_u bf[2];
        #pragma unroll
        for (int ks = 0; ks < 2; ++ks) {
            bf[ks].u[0] = cvt2bf(eb[cur][2 * ks].x,     eb[cur][2 * ks].y);
            bf[ks].u[1] = cvt2bf(eb[cur][2 * ks].z,     eb[cur][2 * ks].w);
            bf[ks].u[2] = cvt2bf(eb[cur][2 * ks + 1].x, eb[cur][2 * ks + 1].y);
            bf[ks].u[3] = cvt2bf(eb[cur][2 * ks + 1].z, eb[cur][2 * ks + 1].w);
        }
        #pragma unroll
        for (int ks = 0; ks < 2; ++ks)
            #pragma unroll
            for (int s = 0; s < 4; ++s) {
                frag_u af;
                af.u4 = *(const uint4*)(ap + (size_t)s * 16 * Dd + c * 64 + ks * 32);
                acc[s] = __builtin_amdgcn_mfma_f32_16x16x32_bf16(
                    af.s8, bf[ks].s8, acc[s], 0, 0, 0);
            }
    }

    __shared__ float bpart[4][64];
    float e[4][4];
    #pragma unroll
    for (int s = 0; s < 4; ++s)
        #pragma unroll
        for (int r = 0; r < 4; ++r) {
            float v = vn ? __expf(acc[s][r]) : 0.f;
            e[s][r] = v;
            if (vn) out[(size_t)(s * 16 + quad * 4 + r) * NC + n] = v;
        }
    #pragma unroll
    for (int s = 0; s < 4; ++s)
        #pragma unroll
        for (int r = 0; r < 4; ++r) {
            float v = e[s][r];
            v += __shfl_xor(v, 1, 64); v += __shfl_xor(v, 2, 64);
            v += __shfl_xor(v, 4, 64); v += __shfl_xor(v, 8, 64);
            if (col == 0) bpart[wave][s * 16 + quad * 4 + r] = v;
        }
    __syncthreads();
    if (tid < 64)
        partials[(size_t)blockIdx.x * 64 + tid] =
            bpart[0][tid] + bpart[1][tid] + bpart[2][tid] + bpart[3][tid];
}

// ---------------------------------------------------------------------------
// K3b: rsum[b] = 1 / sum_k partials[k][b]   grid(64): one b per block
// ---------------------------------------------------------------------------
__global__ __launch_bounds__(256)
void k3b_reduce(const float* __restrict__ partials,
                float* __restrict__ rsum)
{
    const int b = blockIdx.x, tid = threadIdx.x;
    float a = 0.f;
    for (int k = tid; k < NBLK3; k += 256)
        a += partials[(size_t)k * 64 + b];
    a += __shfl_xor(a, 1, 64);  a += __shfl_xor(a, 2, 64);
    a += __shfl_xor(a, 4, 64);  a += __shfl_xor(a, 8, 64);
    a += __shfl_xor(a, 16, 64); a += __shfl_xor(a, 32, 64);
    __shared__ float wsum[4];
    if ((tid & 63) == 0) wsum[tid >> 6] = a;
    __syncthreads();
    if (tid == 0)
        rsum[b] = 1.f / (wsum[0] + wsum[1] + wsum[2] + wsum[3]);
}

// ---------------------------------------------------------------------------
// K4: out[b][n] *= rsum[b]
// ---------------------------------------------------------------------------
__global__ __launch_bounds__(256)
void k4_scale(float* __restrict__ out, const float* __restrict__ rsum)
{
    const int b  = blockIdx.y;
    const int n4 = (blockIdx.x * 256 + threadIdx.x) * 4;
    if (n4 >= NC) return;
    const float r = rsum[b];
    float4* p = (float4*)(out + (size_t)b * NC + n4);
    float4 v = *p;
    v.x *= r; v.y *= r; v.z *= r; v.w *= r;
    *p = v;
}

extern "C" void kernel_launch(void* const* d_in, const int* in_sizes, int n_in,
                              void* d_out, int out_size, void* d_ws, size_t ws_size,
                              hipStream_t stream)
{
    const float* x      = (const float*)d_in[0];
    const float* embed  = (const float*)d_in[1];
    const float* conv_w = (const float*)d_in[2];
    const float* conv_b = (const float*)d_in[3];
    const float* lin_w  = (const float*)d_in[4];
    const float* lin_b  = (const float*)d_in[5];
    float* out = (float*)d_out;
    float* ws  = (float*)d_ws;

    // workspace layout (floats) — every region fully written before read;
    // no memset required.
    unsigned short* wpack = (unsigned short*)ws;            // 131072 shorts
    float* pmax   = ws + 65536;                             // 64*16*1024 = 1,048,576
    float* pooled = ws + 1114112;                           // 65536
    float* out2   = ws + 1179648;                           // 65536
    unsigned short* xnbf = (unsigned short*)(ws + 1245184); // 65536 bf16
    float* partials = ws + 1277952;                         // 50048
    float* rsum   = ws + 1328000;                           // 64

    k0_pack_w   <<<dim3(64),      256, 0, stream>>>(conv_w, wpack);
    k1_conv_mfma<<<dim3(64, 16),  256, 0, stream>>>(x, wpack, pmax);
    k1b_pool    <<<dim3(256),     256, 0, stream>>>(pmax, conv_b, pooled);
    k2_linear   <<<dim3(64, 4),   256, 0, stream>>>(pooled, lin_w, lin_b, out2);
    k2b_norm_cvt<<<dim3(64),      256, 0, stream>>>(out2, xnbf);
    k3_logits_mfma<<<dim3(NBLK3), 256, 0, stream>>>(embed, xnbf, out, partials);
    k3b_reduce  <<<dim3(64),      256, 0, stream>>>(partials, rsum);
    k4_scale    <<<dim3(49, 64),  256, 0, stream>>>(out, rsum);
}